// Round 9
// baseline (237.028 us; speedup 1.0000x reference)
//
#include <hip/hip_runtime.h>
#include <cstddef>

#define NB 32
#define NF 64
#define NL 8192
#define NP 96
#define NH 8
#define TSPLIT 16

// ws layout in floats:
#define WS_MEAN 0           // 2048
#define WS_STD  2048        // 2048
#define WS_RSTD 4096        // 2048
#define WS_KV   6144        // NB*NH*64 = 16384
#define WS_Z    22528       // NB*NH*8  = 2048
#define WS_OUT2 24576       // NB*NP*NF = 196608 -> ends 221184
#define WS_MUN  221184      // NB*NL = 262144
#define WS_RSN  483328      // NB*NL = 262144
#define WS_WLB  745472      // NP*NL bf16 = 393216 floats
#define WS_XNB  1138688     // NB*NF*NL bf16 = 8388608 floats
#define WS_YT   9527296     // NB*NF*NL bf16 = 8388608 floats
#define WS_XB   17915904    // NB*NF*NL bf16 = 8388608 floats (total ~105 MB)

typedef __bf16 bfx8 __attribute__((ext_vector_type(8)));
typedef float f32x4 __attribute__((ext_vector_type(4)));
#define MFMA16(a, b, c) __builtin_amdgcn_mfma_f32_16x16x32_bf16((a), (b), (c), 0, 0, 0)

// ---- bf16 helpers (RNE) ----
__device__ __forceinline__ unsigned short f2bf(float f) {
  unsigned u = __float_as_uint(f);
  unsigned r = u + 0x7FFFu + ((u >> 16) & 1u);
  return (unsigned short)(r >> 16);
}
__device__ __forceinline__ unsigned packbf2(float lo, float hi) {
  return (unsigned)f2bf(lo) | ((unsigned)f2bf(hi) << 16);
}
__device__ __forceinline__ float bflo(unsigned d) { return __uint_as_float(d << 16); }
__device__ __forceinline__ float bfhi(unsigned d) { return __uint_as_float(d & 0xFFFF0000u); }
__device__ __forceinline__ float bf1(unsigned short s) { return __uint_as_float(((unsigned)s) << 16); }

__device__ __forceinline__ bfx8 ldfrag(const unsigned short* p) {
  uint4 u = *(const uint4*)p;
  return __builtin_bit_cast(bfx8, u);
}

// ---------------- K1: RevIN stats per (b,f) + bf16 x copy ----------------
__global__ __launch_bounds__(256) void k_stats(const float* __restrict__ x,
                                               float* __restrict__ wmean,
                                               float* __restrict__ wstd,
                                               float* __restrict__ wrstd,
                                               unsigned short* __restrict__ xb) {
  int bf = blockIdx.x;
  int tid = threadIdx.x;
  const float4* row4 = (const float4*)(x + (size_t)bf * NL);
  unsigned short* xrow = xb + (size_t)bf * NL;
  float s1 = 0.f, s2 = 0.f;
#pragma unroll
  for (int i = 0; i < NL / 4 / 256; i++) {
    float4 v = row4[tid + i * 256];
    s1 += v.x + v.y + v.z + v.w;
    s2 += v.x * v.x + v.y * v.y + v.z * v.z + v.w * v.w;
    uint2 o;
    o.x = packbf2(v.x, v.y);
    o.y = packbf2(v.z, v.w);
    *(uint2*)&xrow[(tid + i * 256) * 4] = o;
  }
  __shared__ float r1[256], r2[256];
  r1[tid] = s1; r2[tid] = s2;
  __syncthreads();
  for (int off = 128; off > 0; off >>= 1) {
    if (tid < off) { r1[tid] += r1[tid + off]; r2[tid] += r2[tid + off]; }
    __syncthreads();
  }
  if (tid == 0) {
    float m = r1[0] * (1.f / NL);
    float var = (r2[0] - (float)NL * m * m) * (1.f / (NL - 1));
    float sd = sqrtf(fmaxf(var, 0.f)) + 1e-5f;
    wmean[bf] = m;
    wstd[bf] = sd;
    wrstd[bf] = 1.f / sd;
  }
}

// ---------------- K1b: Wlin fp32 -> bf16 tiled [l/32][96 p][32 l] ----------------
__global__ __launch_bounds__(256) void k_wlb(const float* __restrict__ Wlin,
                                             unsigned short* __restrict__ wlb) {
  int i = blockIdx.x * 256 + threadIdx.x;   // NP*NL/8 threads
  int p = i >> 10;                          // NL/8 = 1024
  int l8 = (i & 1023) * 8;
  float4 va = *(const float4*)&Wlin[(size_t)p * NL + l8];
  float4 vb = *(const float4*)&Wlin[(size_t)p * NL + l8 + 4];
  uint4 o;
  o.x = packbf2(va.x, va.y); o.y = packbf2(va.z, va.w);
  o.z = packbf2(vb.x, vb.y); o.w = packbf2(vb.z, vb.w);
  *(uint4*)&wlb[(((size_t)(l8 >> 5)) * NP + p) * 32 + (l8 & 31)] = o;
}

// ---------------- K2: K/V projection (MFMA) + KV,Z accumulation + xn export ----------------
// 256 threads, 128 l per block, grid NB*64.  LDS 40960 B -> 4 blocks/CU.
__global__ __launch_bounds__(256, 4) void k_kv(
    const unsigned short* __restrict__ xb,
    const float* __restrict__ gamma, const float* __restrict__ beta,
    const float* __restrict__ lnw, const float* __restrict__ lnb,
    const float* __restrict__ Wk, const float* __restrict__ bk,
    const float* __restrict__ Wv, const float* __restrict__ bv,
    const float* __restrict__ wmean, const float* __restrict__ wrstd,
    float* __restrict__ wKV, float* __restrict__ wZ,
    float* __restrict__ wmun, float* __restrict__ wrsn,
    unsigned short* __restrict__ xnb) {
  __shared__ __align__(16) char smem[40960];
  unsigned short* hA  = (unsigned short*)smem;            // [128][72] xn bf16
  unsigned short* WkB = (unsigned short*)(smem + 18432);  // [64 j][72 f] folded
  unsigned short* WvB = (unsigned short*)(smem + 27648);  // [64 j][72 f] folded
  unsigned short* pK  = (unsigned short*)smem;            // overlay: [64 j][136 l]
  unsigned short* pV  = (unsigned short*)(smem + 17408);  // overlay: [64 j][136 l]
  float* SkT   = (float*)(smem + 36864);  // [256] Sk|Tk|Sv|Tv
  float* mun   = (float*)(smem + 37888);  // [128]
  float* rsn   = (float*)(smem + 38400);  // [128]
  float* pmom  = (float*)(smem + 38912);  // [2][128][2] s1,s2 partials

  const int tid = threadIdx.x;
  const int b = blockIdx.x >> 6;
  const int tI = blockIdx.x & 63;
  const int L0 = tI * 128;
  const int lane = tid & 63, wv = tid >> 6;
  const int mm = lane & 15, qd = lane >> 4;

  // ---- phase 0: stage Wk/Wv rows (lnw-folded bf16); Tk/Tv via 4-lane shuffle ----
  {
    int jj = tid >> 2, g = tid & 3;
    int f0 = g * 16;
    float tkp = 0.f, tvp = 0.f;
#pragma unroll
    for (int i = 0; i < 4; i++) {
      int f = f0 + i * 4;
      float4 wk4 = *(const float4*)&Wk[jj * NF + f];
      float4 wv4 = *(const float4*)&Wv[jj * NF + f];
      float4 lw  = *(const float4*)&lnw[f];
      float4 lb  = *(const float4*)&lnb[f];
      uint2 pk2, pv2;
      pk2.x = packbf2(wk4.x * lw.x, wk4.y * lw.y);
      pk2.y = packbf2(wk4.z * lw.z, wk4.w * lw.w);
      pv2.x = packbf2(wv4.x * lw.x, wv4.y * lw.y);
      pv2.y = packbf2(wv4.z * lw.z, wv4.w * lw.w);
      *(uint2*)&WkB[jj * 72 + f] = pk2;
      *(uint2*)&WvB[jj * 72 + f] = pv2;
      tkp += lb.x * wk4.x + lb.y * wk4.y + lb.z * wk4.z + lb.w * wk4.w;
      tvp += lb.x * wv4.x + lb.y * wv4.y + lb.z * wv4.z + lb.w * wv4.w;
    }
    tkp += __shfl_xor(tkp, 1, 64); tkp += __shfl_xor(tkp, 2, 64);
    tvp += __shfl_xor(tvp, 1, 64); tvp += __shfl_xor(tvp, 2, 64);
    if (g == 0) {
      SkT[64 + jj]  = tkp + bk[jj];
      SkT[192 + jj] = tvp + bv[jj];
    }
  }

  // ---- phase 1: xn (RevIN affine on bf16 x), raw-moment partials, pack to LDS ----
  {
    const int sel = tid >> 7;      // 0,1 -> f half
    const int l = tid & 127;
    const int fbase = sel * 32;
    float s1 = 0.f, s2 = 0.f;
    float xn2[32];
#pragma unroll
    for (int i = 0; i < 32; i++) {
      int f = fbase + i;
      float v = bf1(xb[((size_t)(b * NF + f)) * NL + L0 + l]);
      v = (v - wmean[b * NF + f]) * wrstd[b * NF + f] * gamma[f] + beta[f];
      xn2[i] = v; s1 += v; s2 += v * v;
    }
    pmom[sel * 256 + l * 2] = s1;
    pmom[sel * 256 + l * 2 + 1] = s2;
    unsigned* hrow = (unsigned*)&hA[l * 72];
#pragma unroll
    for (int i = 0; i < 16; i++)
      hrow[fbase / 2 + i] = packbf2(xn2[2 * i], xn2[2 * i + 1]);
  }
  __syncthreads();

  // ---- mu/rs (raw moments) by tid<128; S finalize by tid in [128,256) ----
  if (tid < 128) {
    float s1 = pmom[tid * 2] + pmom[256 + tid * 2];
    float s2 = pmom[tid * 2 + 1] + pmom[256 + tid * 2 + 1];
    float mu = s1 * (1.f / NF);
    float var = s2 * (1.f / NF) - mu * mu;
    float rs = rsqrtf(fmaxf(var, 0.f) + 1e-5f);
    mun[tid] = mu; rsn[tid] = rs;
    wmun[(size_t)b * NL + L0 + tid] = mu;
    wrsn[(size_t)b * NL + L0 + tid] = rs;
  } else {
    int sel = (tid >> 6) - 2, j = tid & 63;
    const unsigned* wr = (const unsigned*)((sel ? WvB : WkB) + j * 72);
    float s = 0.f;
#pragma unroll
    for (int i = 0; i < 32; i++) { unsigned d = wr[i]; s += bflo(d) + bfhi(d); }
    SkT[sel * 128 + j] = s;
  }

  // ---- export xn tile to global (LDS-image order [l][f]) ----
  {
    int row = tid >> 1, half = tid & 1;
    const uint4* s4 = (const uint4*)&hA[row * 72 + half * 32];
    uint4* d4 = (uint4*)(xnb + (((size_t)(b * 64 + tI) * 128 + row) * 64 + half * 32));
    d4[0] = s4[0]; d4[1] = s4[1]; d4[2] = s4[2]; d4[3] = s4[3];
  }
  __syncthreads();

  // ---- projection MFMA: out[l][j], wave handles 32 l x 64 j ----
  const f32x4 fz = {0.f, 0.f, 0.f, 0.f};
  f32x4 kacc[2][4], vacc[2][4];
#pragma unroll
  for (int i = 0; i < 2; i++)
#pragma unroll
    for (int jt = 0; jt < 4; jt++) { kacc[i][jt] = fz; vacc[i][jt] = fz; }

#pragma unroll
  for (int kc = 0; kc < 2; kc++) {
    bfx8 a0 = ldfrag(&hA[(wv * 32 + mm) * 72 + kc * 32 + qd * 8]);
    bfx8 a1 = ldfrag(&hA[(wv * 32 + 16 + mm) * 72 + kc * 32 + qd * 8]);
#pragma unroll
    for (int jt = 0; jt < 4; jt++) {
      bfx8 bkf = ldfrag(&WkB[(jt * 16 + mm) * 72 + kc * 32 + qd * 8]);
      bfx8 bvf = ldfrag(&WvB[(jt * 16 + mm) * 72 + kc * 32 + qd * 8]);
      kacc[0][jt] = MFMA16(a0, bkf, kacc[0][jt]);
      kacc[1][jt] = MFMA16(a1, bkf, kacc[1][jt]);
      vacc[0][jt] = MFMA16(a0, bvf, vacc[0][jt]);
      vacc[1][jt] = MFMA16(a1, bvf, vacc[1][jt]);
    }
  }

  // ---- postfix: K = rs*(raw - mu*Sk) + Tk -> phi;  V likewise (no phi) ----
#pragma unroll
  for (int lt2 = 0; lt2 < 2; lt2++) {
    float4 mu4 = *(const float4*)&mun[wv * 32 + lt2 * 16 + qd * 4];
    float4 rs4 = *(const float4*)&rsn[wv * 32 + lt2 * 16 + qd * 4];
    float muv[4] = {mu4.x, mu4.y, mu4.z, mu4.w};
    float rsv[4] = {rs4.x, rs4.y, rs4.z, rs4.w};
#pragma unroll
    for (int jt = 0; jt < 4; jt++) {
      int j = jt * 16 + mm;
      float Sk = SkT[j], Tk = SkT[64 + j], Sv = SkT[128 + j], Tv = SkT[192 + j];
#pragma unroll
      for (int r = 0; r < 4; r++) {
        float kk = rsv[r] * (kacc[lt2][jt][r] - muv[r] * Sk) + Tk;
        kacc[lt2][jt][r] = (kk > 0.f) ? (kk + 1.f) : __expf(kk);
        vacc[lt2][jt][r] = rsv[r] * (vacc[lt2][jt][r] - muv[r] * Sv) + Tv;
      }
    }
  }
  __syncthreads();   // hA/WkB/WvB dead -> overlay with pK/pV

  // ---- pack phi(K), V into [64 j][136 l] bf16 ----
#pragma unroll
  for (int lt2 = 0; lt2 < 2; lt2++) {
    int l0 = wv * 32 + lt2 * 16 + qd * 4;
#pragma unroll
    for (int jt = 0; jt < 4; jt++) {
      int j = jt * 16 + mm;
      uint2 dk, dv;
      dk.x = packbf2(kacc[lt2][jt][0], kacc[lt2][jt][1]);
      dk.y = packbf2(kacc[lt2][jt][2], kacc[lt2][jt][3]);
      dv.x = packbf2(vacc[lt2][jt][0], vacc[lt2][jt][1]);
      dv.y = packbf2(vacc[lt2][jt][2], vacc[lt2][jt][3]);
      *(uint2*)&pK[j * 136 + l0] = dk;
      *(uint2*)&pV[j * 136 + l0] = dv;
    }
  }
  __syncthreads();

  // ---- KV reduction MFMA: wave = head pair {2wv, 2wv+1}; A=phi(K)^T, B=V ----
  {
    f32x4 racc = fz;
#pragma unroll
    for (int kb = 0; kb < 4; kb++) {
      bfx8 ak = ldfrag(&pK[(wv * 16 + mm) * 136 + kb * 32 + qd * 8]);
      bfx8 bv8 = ldfrag(&pV[(wv * 16 + mm) * 136 + kb * 32 + qd * 8]);
      racc = MFMA16(ak, bv8, racc);
    }
    int eh = mm >> 3, e = mm & 7;
#pragma unroll
    for (int r = 0; r < 4; r++) {
      int row = qd * 4 + r;
      if ((row >> 3) == eh)
        atomicAdd(&wKV[(b * NH + wv * 2 + eh) * 64 + (row & 7) * 8 + e], racc[r]);
    }
  }
  // ---- Z: row sums of pK ----
  if (tid < 64) {
    const unsigned* kr = (const unsigned*)&pK[tid * 136];
    float zs = 0.f;
#pragma unroll
    for (int i = 0; i < 64; i++) { unsigned d = kr[i]; zs += bflo(d) + bfhi(d); }
    atomicAdd(&wZ[b * 64 + tid], zs);
  }
}

// ---------------- K3: Q MFMA + readout + O MFMA + residual -> yT tiled bf16 ----------------
// 256 threads, 128 l, grid NB*64.  LDS 40704 B -> 4 blocks/CU.
__global__ __launch_bounds__(256, 4) void k_qy(
    const unsigned short* __restrict__ xnb,
    const float* __restrict__ lnw, const float* __restrict__ lnb,
    const float* __restrict__ Wq, const float* __restrict__ bq,
    const float* __restrict__ Wo, const float* __restrict__ bo,
    const float* __restrict__ wmun, const float* __restrict__ wrsn,
    const float* __restrict__ wKV, const float* __restrict__ wZ,
    unsigned short* __restrict__ ytb) {
  __shared__ __align__(16) char smem[40704];
  unsigned short* hA  = (unsigned short*)smem;             // [128][72] xn bf16 -> overlaid by att
  unsigned short* qaA = (unsigned short*)smem;             // [128 l][72] phi(Q)/att
  unsigned short* WqB = (unsigned short*)(smem + 18432);   // [64 j][72 f] folded
  unsigned short* WoB = (unsigned short*)(smem + 27648);   // [64 f][72 e]
  float* kvz   = (float*)(smem + 36864);  // [576]
  float* mun   = (float*)(smem + 39168);  // [128]
  float* rsn   = (float*)(smem + 39680);  // [128]
  float* SqTq  = (float*)(smem + 40192);  // [128]

  const int tid = threadIdx.x;
  const int b = blockIdx.x >> 6;
  const int tI = blockIdx.x & 63;
  const int L0 = tI * 128;
  const int lane = tid & 63, wv = tid >> 6;
  const int mm = lane & 15, qd = lane >> 4;
  const unsigned short* xtile = xnb + (size_t)(b * 64 + tI) * 128 * 64;

  // ---- phase 0: stage Wq (folded, Tq via shuffle) + Wo rows + kvz + xn tile + mu/rs ----
  {
    int jj = tid >> 2, g = tid & 3;
    int f0 = g * 16;
    float tqp = 0.f;
#pragma unroll
    for (int i = 0; i < 4; i++) {
      int f = f0 + i * 4;
      float4 wq4 = *(const float4*)&Wq[jj * NF + f];
      float4 wo4 = *(const float4*)&Wo[jj * NF + f];
      float4 lw  = *(const float4*)&lnw[f];
      float4 lb  = *(const float4*)&lnb[f];
      uint2 pq2, po2;
      pq2.x = packbf2(wq4.x * lw.x, wq4.y * lw.y);
      pq2.y = packbf2(wq4.z * lw.z, wq4.w * lw.w);
      po2.x = packbf2(wo4.x, wo4.y);
      po2.y = packbf2(wo4.z, wo4.w);
      *(uint2*)&WqB[jj * 72 + f] = pq2;
      *(uint2*)&WoB[jj * 72 + f] = po2;
      tqp += lb.x * wq4.x + lb.y * wq4.y + lb.z * wq4.z + lb.w * wq4.w;
    }
    tqp += __shfl_xor(tqp, 1, 64); tqp += __shfl_xor(tqp, 2, 64);
    if (g == 0) SqTq[64 + jj] = tqp + bq[jj];
  }
  for (int i = tid; i < 576; i += 256)
    kvz[i] = (i < 512) ? wKV[b * 512 + i] : wZ[b * 64 + i - 512];
  {
    int row = tid >> 1, half = tid & 1;
    const uint4* s4 = (const uint4*)(xtile + (size_t)row * 64 + half * 32);
    uint4 u0 = s4[0], u1 = s4[1], u2 = s4[2], u3 = s4[3];
    uint4* d4 = (uint4*)&hA[row * 72 + half * 32];
    d4[0] = u0; d4[1] = u1; d4[2] = u2; d4[3] = u3;
  }
  if (tid < 128) {
    mun[tid] = wmun[(size_t)b * NL + L0 + tid];
    rsn[tid] = wrsn[(size_t)b * NL + L0 + tid];
  }
  __syncthreads();

  if (tid < 64) {
    const unsigned* wr = (const unsigned*)(WqB + tid * 72);
    float s = 0.f;
#pragma unroll
    for (int i = 0; i < 32; i++) { unsigned d = wr[i]; s += bflo(d) + bfhi(d); }
    SqTq[tid] = s;
  }
  __syncthreads();

  const f32x4 fz = {0.f, 0.f, 0.f, 0.f};

  // ---- Q-MFMA; postfix+phi scatters into qaA (overlay of hA, own l-rows only) ----
  {
    f32x4 qacc[2][4];
#pragma unroll
    for (int i = 0; i < 2; i++)
#pragma unroll
      for (int jt = 0; jt < 4; jt++) qacc[i][jt] = fz;
#pragma unroll
    for (int kc = 0; kc < 2; kc++) {
      bfx8 a0 = ldfrag(&hA[(wv * 32 + mm) * 72 + kc * 32 + qd * 8]);
      bfx8 a1 = ldfrag(&hA[(wv * 32 + 16 + mm) * 72 + kc * 32 + qd * 8]);
#pragma unroll
      for (int jt = 0; jt < 4; jt++) {
        bfx8 bqf = ldfrag(&WqB[(jt * 16 + mm) * 72 + kc * 32 + qd * 8]);
        qacc[0][jt] = MFMA16(a0, bqf, qacc[0][jt]);
        qacc[1][jt] = MFMA16(a1, bqf, qacc[1][jt]);
      }
    }
#pragma unroll
    for (int lt2 = 0; lt2 < 2; lt2++) {
      float4 mu4 = *(const float4*)&mun[wv * 32 + lt2 * 16 + qd * 4];
      float4 rs4 = *(const float4*)&rsn[wv * 32 + lt2 * 16 + qd * 4];
      float muv[4] = {mu4.x, mu4.y, mu4.z, mu4.w};
      float rsv[4] = {rs4.x, rs4.y, rs4.z, rs4.w};
      int l0 = wv * 32 + lt2 * 16 + qd * 4;
#pragma unroll
      for (int jt = 0; jt < 4; jt++) {
        int j = jt * 16 + mm;
        float Sj = SqTq[j], Tj = SqTq[64 + j];
#pragma unroll
        for (int r = 0; r < 4; r++) {
          float q = rsv[r] * (qacc[lt2][jt][r] - muv[r] * Sj) + Tj;
          q = (q > 0.f) ? (q + 1.f) : __expf(q);
          qaA[(l0 + r) * 72 + j] = f2bf(q);
        }
      }
    }
  }
  __syncthreads();

  // ---- readout in place: thread = (4 l, 1 head) tile of qaA ----
  {
    int lt = tid & 31, hd = tid >> 5;
    int lbase = lt * 4;
    float qv[4][8];
#pragma unroll
    for (int i = 0; i < 4; i++) {
      uint4 u = *(const uint4*)&qaA[(lbase + i) * 72 + hd * 8];
      qv[i][0] = bflo(u.x); qv[i][1] = bfhi(u.x);
      qv[i][2] = bflo(u.y); qv[i][3] = bfhi(u.y);
      qv[i][4] = bflo(u.z); qv[i][5] = bfhi(u.z);
      qv[i][6] = bflo(u.w); qv[i][7] = bfhi(u.w);
    }
    float att[4][8], nrm[4];
#pragma unroll
    for (int i = 0; i < 4; i++) {
      nrm[i] = 1e-6f;
#pragma unroll
      for (int e = 0; e < 8; e++) att[i][e] = 0.f;
    }
#pragma unroll
    for (int d = 0; d < 8; d++) {
      float zd = kvz[512 + hd * 8 + d];
      float4 kva = *(const float4*)&kvz[hd * 64 + d * 8];
      float4 kvb = *(const float4*)&kvz[hd * 64 + d * 8 + 4];
#pragma unroll
      for (int i = 0; i < 4; i++) {
        float qq = qv[i][d];
        nrm[i] = fmaf(qq, zd, nrm[i]);
        att[i][0] = fmaf(qq, kva.x, att[i][0]);
        att[i][1] = fmaf(qq, kva.y, att[i][1]);
        att[i][2] = fmaf(qq, kva.z, att[i][2]);
        att[i][3] = fmaf(qq, kva.w, att[i][3]);
        att[i][4] = fmaf(qq, kvb.x, att[i][4]);
        att[i][5] = fmaf(qq, kvb.y, att[i][5]);
        att[i][6] = fmaf(qq, kvb.z, att[i][6]);
        att[i][7] = fmaf(qq, kvb.w, att[i][7]);
      }
    }
#pragma unroll
    for (int i = 0; i < 4; i++) {
      float inv = 1.f / nrm[i];
      uint4 o;
      o.x = packbf2(att[i][0] * inv, att[i][1] * inv);
      o.y = packbf2(att[i][2] * inv, att[i][3] * inv);
      o.z = packbf2(att[i][4] * inv, att[i][5] * inv);
      o.w = packbf2(att[i][6] * inv, att[i][7] * inv);
      *(uint4*)&qaA[(lbase + i) * 72 + hd * 8] = o;
    }
  }
  __syncthreads();

  // ---- O-MFMA: y[l][f] = att[l][e] . Wo[f][e]; epilogue -> yt tiled ----
  {
    f32x4 yacc[2][4];
#pragma unroll
    for (int i = 0; i < 2; i++)
#pragma unroll
      for (int ft = 0; ft < 4; ft++) yacc[i][ft] = fz;
#pragma unroll
    for (int ec = 0; ec < 2; ec++) {
      bfx8 a0 = ldfrag(&qaA[(wv * 32 + mm) * 72 + ec * 32 + qd * 8]);
      bfx8 a1 = ldfrag(&qaA[(wv * 32 + 16 + mm) * 72 + ec * 32 + qd * 8]);
#pragma unroll
      for (int ft = 0; ft < 4; ft++) {
        bfx8 bof = ldfrag(&WoB[(ft * 16 + mm) * 72 + ec * 32 + qd * 8]);
        yacc[0][ft] = MFMA16(a0, bof, yacc[0][ft]);
        yacc[1][ft] = MFMA16(a1, bof, yacc[1][ft]);
      }
    }
    // epilogue: + xn residual (global xnb, L1-hot) + bo -> tiled bf16 store
#pragma unroll
    for (int lt2 = 0; lt2 < 2; lt2++) {
      int l0 = wv * 32 + lt2 * 16 + qd * 4;
#pragma unroll
      for (int ft = 0; ft < 4; ft++) {
        int ff = ft * 16 + mm;
        float bof = bo[ff];
        float v0 = yacc[lt2][ft][0] + bf1(xtile[(size_t)(l0 + 0) * 64 + ff]) + bof;
        float v1 = yacc[lt2][ft][1] + bf1(xtile[(size_t)(l0 + 1) * 64 + ff]) + bof;
        float v2 = yacc[lt2][ft][2] + bf1(xtile[(size_t)(l0 + 2) * 64 + ff]) + bof;
        float v3 = yacc[lt2][ft][3] + bf1(xtile[(size_t)(l0 + 3) * 64 + ff]) + bof;
        uint2 o2;
        o2.x = packbf2(v0, v1);
        o2.y = packbf2(v2, v3);
        size_t idx = (((size_t)b * (NL / 32) + (L0 >> 5) + wv) * 64 + ff) * 32 + lt2 * 16 + qd * 4;
        *(uint2*)&ytb[idx] = o2;
      }
    }
  }
}

// ---------------- K4: temporal GEMM via MFMA, tiled layouts, no LDS ----------------
// ytb: [b][l/32][64 f][32 l], wlb: [l/32][96 p][32 l]
__global__ __launch_bounds__(256) void k_temporal(
    const unsigned short* __restrict__ ytb, const unsigned short* __restrict__ wlb,
    float* __restrict__ out2) {
  const int tid = threadIdx.x, lane = tid & 63, wvx = tid >> 6;
  const int mm = lane & 15, qd = lane >> 4;
  const int b = blockIdx.x / TSPLIT;
  const int kc = blockIdx.x % TSPLIT;
  const f32x4 fz = {0.f, 0.f, 0.f, 0.f};
  f32x4 acc[6];
#pragma unroll
  for (int pt = 0; pt < 6; pt++) acc[pt] = fz;

#pragma unroll 2
  for (int ks = 0; ks < (NL / 32) / TSPLIT; ks++) {
    int lg = kc * ((NL / 32) / TSPLIT) + ks;
    bfx8 bfr = ldfrag(&ytb[(((size_t)b * (NL / 32) + lg) * 64 + wvx * 16 + mm) * 32 + qd * 8]);
#pragma unroll
    for (int pt = 0; pt < 6; pt++) {
      bfx8 afr = ldfrag(&wlb[((size_t)lg * NP + pt * 16 + mm) * 32 + qd * 8]);
      acc[pt] = MFMA16(afr, bfr, acc[pt]);
    }
  }
  const int ff = wvx * 16 + mm;
#pragma unroll
  for (int pt = 0; pt < 6; pt++) {
#pragma unroll
    for (int r = 0; r < 4; r++) {
      int p = pt * 16 + qd * 4 + r;
      atomicAdd(&out2[((size_t)(b * NP + p)) * NF + ff], acc[pt][r]);
    }
  }
}

// ---------------- K5: +blin, RevIN denorm, projector ----------------
__global__ __launch_bounds__(64) void k_final(
    const float* __restrict__ out2, const float* __restrict__ blin,
    const float* __restrict__ gamma, const float* __restrict__ beta,
    const float* __restrict__ wmean, const float* __restrict__ wstd,
    const float* __restrict__ Wp, const float* __restrict__ bp,
    float* __restrict__ out) {
  int b = blockIdx.x / NP;
  int p = blockIdx.x % NP;
  int f = threadIdx.x;
  float v = out2[((size_t)(b * NP + p)) * NF + f] + blin[p];
  v = (v - beta[f]) / gamma[f];
  v = v * wstd[b * NF + f] + wmean[b * NF + f];
  float s = v * Wp[f];
#pragma unroll
  for (int off = 32; off > 0; off >>= 1)
    s += __shfl_down(s, off, 64);
  if (f == 0) out[blockIdx.x] = s + bp[0];
}

extern "C" void kernel_launch(void* const* d_in, const int* in_sizes, int n_in,
                              void* d_out, int out_size, void* d_ws, size_t ws_size,
                              hipStream_t stream) {
  const float* x     = (const float*)d_in[0];
  const float* gamma = (const float*)d_in[1];
  const float* beta  = (const float*)d_in[2];
  const float* lnw   = (const float*)d_in[3];
  const float* lnb   = (const float*)d_in[4];
  const float* Wq    = (const float*)d_in[5];
  const float* bq    = (const float*)d_in[6];
  const float* Wk    = (const float*)d_in[7];
  const float* bk    = (const float*)d_in[8];
  const float* Wv    = (const float*)d_in[9];
  const float* bv    = (const float*)d_in[10];
  const float* Wo    = (const float*)d_in[11];
  const float* bo    = (const float*)d_in[12];
  const float* Wlin  = (const float*)d_in[13];
  const float* blin  = (const float*)d_in[14];
  const float* Wp    = (const float*)d_in[15];
  const float* bp    = (const float*)d_in[16];
  float* out = (float*)d_out;
  float* ws  = (float*)d_ws;

  float* wmean = ws + WS_MEAN;
  float* wstd  = ws + WS_STD;
  float* wrstd = ws + WS_RSTD;
  float* wKV   = ws + WS_KV;
  float* wZ    = ws + WS_Z;
  float* wout2 = ws + WS_OUT2;
  float* wmun  = ws + WS_MUN;
  float* wrsn  = ws + WS_RSN;
  unsigned short* wlb = (unsigned short*)(ws + WS_WLB);
  unsigned short* xnb = (unsigned short*)(ws + WS_XNB);
  unsigned short* ytb = (unsigned short*)(ws + WS_YT);
  unsigned short* xb  = (unsigned short*)(ws + WS_XB);

  (void)hipMemsetAsync(wKV, 0, (size_t)(16384 + 2048 + 196608) * sizeof(float), stream);

  k_stats<<<NB * NF, 256, 0, stream>>>(x, wmean, wstd, wrstd, xb);
  k_wlb<<<NP * NL / 8 / 256, 256, 0, stream>>>(Wlin, wlb);
  k_kv<<<NB * 64, 256, 0, stream>>>(xb, gamma, beta, lnw, lnb, Wk, bk, Wv, bv,
                                    wmean, wrstd, wKV, wZ, wmun, wrsn, xnb);
  k_qy<<<NB * 64, 256, 0, stream>>>(xnb, lnw, lnb, Wq, bq, Wo, bo,
                                    wmun, wrsn, wKV, wZ, ytb);
  k_temporal<<<NB * TSPLIT, 256, 0, stream>>>(ytb, wlb, wout2);
  k_final<<<NB * NP, 64, 0, stream>>>(wout2, blin, gamma, beta, wmean, wstd, Wp, bp, out);
}